// Round 14
// baseline (183.760 us; speedup 1.0000x reference)
//
#include <hip/hip_runtime.h>
#include <hip/hip_bf16.h>

#define B_ 8
#define T_ 768
#define H_ 128
#define F_ 10

using short8v = __attribute__((ext_vector_type(8))) short;
using f32x4   = __attribute__((ext_vector_type(4))) float;

__device__ __forceinline__ float bf2f(unsigned short s) {
  union { unsigned int u; float f; } w;
  w.u = ((unsigned int)s) << 16;
  return w.f;
}
__device__ __forceinline__ unsigned short f2bf(float x) {
  __hip_bfloat16 h = __float2bfloat16(x);  // RN
  return *reinterpret_cast<unsigned short*>(&h);
}
union Pk8 { uint4 u4; unsigned short s[8]; };

// ---------------------------------------------------------------------------
// r10_PV: V -> row-major fragments (rows = T index, K = H dim), hi/lo. (verified)
// ---------------------------------------------------------------------------
__global__ __launch_bounds__(256) void r10_PV(const float* __restrict__ V,
                                              unsigned short* __restrict__ VFh,
                                              unsigned short* __restrict__ VFl) {
  const int task = blockIdx.x * 256 + threadIdx.x;
  const int b  = task / (T_ * 16);
  const int r  = task % (T_ * 16);
  const int j  = r >> 4;
  const int ko = r & 15;
  const float* src = V + ((size_t)b * T_ + j) * H_ + ko * 8;
  const float4 v0 = *reinterpret_cast<const float4*>(src);
  const float4 v1 = *reinterpret_cast<const float4*>(src + 4);
  const float vv[8] = {v0.x, v0.y, v0.z, v0.w, v1.x, v1.y, v1.z, v1.w};
  Pk8 hi, lo;
#pragma unroll
  for (int e = 0; e < 8; ++e) {
    const unsigned short h = f2bf(vv[e]);
    hi.s[e] = h;
    lo.s[e] = f2bf(vv[e] - bf2f(h));
  }
  const size_t frag = ((size_t)b * 48 + (j >> 4)) * 4 + (ko >> 2);
  const size_t off = frag * 512 + ((size_t)((j & 15) + 16 * (ko & 3))) * 8;
  *reinterpret_cast<uint4*>(VFh + off) = hi.u4;
  *reinterpret_cast<uint4*>(VFl + off) = lo.u4;
}

// ---------------------------------------------------------------------------
// r12_PW2: W -> B-operand fragments (K = h, N = k), hi/lo.  (verified)
// ---------------------------------------------------------------------------
__global__ __launch_bounds__(256) void r12_PW2(const float* __restrict__ W,
                                               unsigned short* __restrict__ WFh,
                                               unsigned short* __restrict__ WFl) {
  const int tid = blockIdx.x * 256 + threadIdx.x;  // < 320*64
  const int frag = tid >> 6;
  const int l    = tid & 63;
  const int f    = frag >> 5;
  const int rest = frag & 31;
  const int n    = rest >> 2;
  const int ks   = rest & 3;
  const int k  = n * 16 + (l & 15);
  const int h0 = ks * 32 + ((l >> 4) * 8);
  Pk8 hi, lo;
#pragma unroll
  for (int e = 0; e < 8; ++e) {
    const float v = W[((size_t)f * H_ + h0 + e) * H_ + k];
    const unsigned short hh = f2bf(v);
    hi.s[e] = hh;
    lo.s[e] = f2bf(v - bf2f(hh));
  }
  const size_t off = (size_t)frag * 512 + (size_t)l * 8;
  *reinterpret_cast<uint4*>(WFh + off) = hi.u4;
  *reinterpret_cast<uint4*>(WFl + off) = lo.u4;
}

// ---------------------------------------------------------------------------
// r11_PW: V -> PV-B fragments (j as K dim, h as N dim), hi/lo.  (verified)
// ---------------------------------------------------------------------------
__global__ __launch_bounds__(256) void r11_PW(const float* __restrict__ V,
                                              unsigned short* __restrict__ VPh,
                                              unsigned short* __restrict__ VPl) {
  const int tid = blockIdx.x * 256 + threadIdx.x;  // < 98304
  const int h    = tid & 127;
  const int rest = tid >> 7;
  const int jo   = rest % 96;
  const int b    = rest / 96;
  const int j0   = jo * 8;

  Pk8 hi, lo;
#pragma unroll
  for (int e = 0; e < 8; ++e) {
    const float v = V[((size_t)b * T_ + j0 + e) * H_ + h];
    const unsigned short hh = f2bf(v);
    hi.s[e] = hh;
    lo.s[e] = f2bf(v - bf2f(hh));
  }
  const size_t frag = ((size_t)b * 8 + (h >> 4)) * 24 + (j0 >> 5);
  const size_t off = frag * 512 + ((size_t)((h & 15) + 16 * ((j0 >> 3) & 3))) * 8;
  *reinterpret_cast<uint4*>(VPh + off) = hi.u4;
  *reinterpret_cast<uint4*>(VPl + off) = lo.u4;
}

// ---------------------------------------------------------------------------
// r12_A: U = V @ W via split-bf16 MFMA -> UF fragments.  (verified compute)
// XCD swizzle: b = blk&7 so UF(b,*) is produced on the XCD that consumes it.
// grid = 960.
// ---------------------------------------------------------------------------
__global__ __launch_bounds__(256) void r12_A(const unsigned short* __restrict__ VFh,
                                             const unsigned short* __restrict__ VFl,
                                             const unsigned short* __restrict__ WFh,
                                             const unsigned short* __restrict__ WFl,
                                             unsigned short* __restrict__ UFh,
                                             unsigned short* __restrict__ UFl) {
  __shared__ __align__(16) float fl[8192];
  const int blk = blockIdx.x;
  const int b     = blk & 7;
  const int local = blk >> 3;  // 0..119
  const int it    = local % 12;
  const int f     = local / 12;
  const int t  = threadIdx.x;
  const int w  = t >> 6;
  const int l  = t & 63;

  short8v Ah[4], Al[4];
#pragma unroll
  for (int ks = 0; ks < 4; ++ks) {
    const size_t off = (((size_t)b * 48 + it * 4 + w) * 4 + ks) * 512 + (size_t)l * 8;
    Ah[ks] = *reinterpret_cast<const short8v*>(VFh + off);
    Al[ks] = *reinterpret_cast<const short8v*>(VFl + off);
  }

  f32x4 acc[8];
#pragma unroll
  for (int n = 0; n < 8; ++n)
#pragma unroll
    for (int q = 0; q < 4; ++q) acc[n][q] = 0.f;

#pragma unroll
  for (int n = 0; n < 8; ++n)
#pragma unroll
    for (int ks = 0; ks < 4; ++ks) {
      const size_t off = ((size_t)(f * 8 + n) * 4 + ks) * 512 + (size_t)l * 8;
      const short8v bh = *reinterpret_cast<const short8v*>(WFh + off);
      const short8v bl = *reinterpret_cast<const short8v*>(WFl + off);
      acc[n] = __builtin_amdgcn_mfma_f32_16x16x32_bf16(Ah[ks], bh, acc[n], 0, 0, 0);
      acc[n] = __builtin_amdgcn_mfma_f32_16x16x32_bf16(Al[ks], bh, acc[n], 0, 0, 0);
      acc[n] = __builtin_amdgcn_mfma_f32_16x16x32_bf16(Ah[ks], bl, acc[n], 0, 0, 0);
    }

#pragma unroll
  for (int n = 0; n < 8; ++n)
#pragma unroll
    for (int q = 0; q < 4; ++q) {
      const int i_loc = w * 16 + (l >> 4) * 4 + q;
      const int k = n * 16 + (l & 15);
      const int ll = (i_loc & 15) + 16 * ((k >> 3) & 3);
      fl[((w * 4 + (k >> 5)) << 9) + ll * 8 + (k & 7)] = acc[n][q];
    }
  __syncthreads();
  const size_t ufbase = ((size_t)(b * F_ + f) * 192 + it * 16) * 512;
#pragma unroll
  for (int rr = 0; rr < 4; ++rr) {
    const int idx = rr * 2048 + t * 8;
    const float4 v0 = *reinterpret_cast<const float4*>(&fl[idx]);
    const float4 v1 = *reinterpret_cast<const float4*>(&fl[idx + 4]);
    const float vv[8] = {v0.x, v0.y, v0.z, v0.w, v1.x, v1.y, v1.z, v1.w};
    Pk8 hi, lo;
#pragma unroll
    for (int e = 0; e < 8; ++e) {
      const unsigned short h = f2bf(vv[e]);
      hi.s[e] = h;
      lo.s[e] = f2bf(vv[e] - bf2f(h));
    }
    *reinterpret_cast<uint4*>(UFh + ufbase + idx) = hi.u4;
    *reinterpret_cast<uint4*>(UFl + ufbase + idx) = lo.u4;
  }
}

// ---------------------------------------------------------------------------
// r14_F: FUSED scores(max over f) + online softmax + PV.  Replaces r10_B+r11_C;
// S never materialized.  Block = (b, 16-row i-tile), grid = 8*48 = 384
// (b = blk&7 -> XCD-pinned).  4 waves; wave w owns jt in {3w,3w+1,3w+2}.
// Score MFMA ≡ r10_B (verified); PV MFMA ≡ r11_C (verified); C/D layout m89.
// ---------------------------------------------------------------------------
__global__ __launch_bounds__(256) void r14_F(const unsigned short* __restrict__ UFh,
                                             const unsigned short* __restrict__ UFl,
                                             const unsigned short* __restrict__ VFh,
                                             const unsigned short* __restrict__ VFl,
                                             const unsigned short* __restrict__ VPh,
                                             const unsigned short* __restrict__ VPl,
                                             float* __restrict__ O) {
  __shared__ __align__(16) unsigned short sP[4][16][72];  // P tile per wave
  __shared__ __align__(16) float sOm[4][16][132];         // PV partials
  __shared__ float sMw[4][16];
  __shared__ float sLw[4][16];

  const int blk  = blockIdx.x;
  const int b    = blk & 7;
  const int it16 = blk >> 3;  // 0..47
  const int t  = threadIdx.x;
  const int w  = t >> 6;
  const int l  = t & 63;
  const int lr = l >> 4;  // 0..3: row group (rows lr*4+q)
  const int lc = l & 15;  // col within fragment

  f32x4 mrow, lrow;
#pragma unroll
  for (int q = 0; q < 4; ++q) { mrow[q] = -3.4e38f; lrow[q] = 0.f; }
  f32x4 acch[8];
#pragma unroll
  for (int n = 0; n < 8; ++n)
#pragma unroll
    for (int q = 0; q < 4; ++q) acch[n][q] = 0.f;

  for (int jj = 0; jj < 3; ++jj) {
    const int jt = w * 3 + jj;  // 0..11

    // ---- scores: S16x64 = max_f U_f(16x128) . V^T(128x64), split-bf16 ----
    short8v Bh[4][4], Bl[4][4];
#pragma unroll
    for (int n = 0; n < 4; ++n)
#pragma unroll
      for (int ks = 0; ks < 4; ++ks) {
        const size_t off =
            (((size_t)b * 48 + jt * 4 + n) * 4 + ks) * 512 + (size_t)l * 8;
        Bh[n][ks] = *reinterpret_cast<const short8v*>(VFh + off);
        Bl[n][ks] = *reinterpret_cast<const short8v*>(VFl + off);
      }

    f32x4 smax[4];
#pragma unroll
    for (int n = 0; n < 4; ++n)
#pragma unroll
      for (int q = 0; q < 4; ++q) smax[n][q] = -3.4e38f;

    for (int f = 0; f < F_; ++f) {
      short8v Ah[4], Al[4];
#pragma unroll
      for (int ks = 0; ks < 4; ++ks) {
        const size_t off =
            (((size_t)(b * F_ + f) * 48 + it16) * 4 + ks) * 512 + (size_t)l * 8;
        Ah[ks] = *reinterpret_cast<const short8v*>(UFh + off);
        Al[ks] = *reinterpret_cast<const short8v*>(UFl + off);
      }
      f32x4 acc[4];
#pragma unroll
      for (int n = 0; n < 4; ++n)
#pragma unroll
        for (int q = 0; q < 4; ++q) acc[n][q] = 0.f;
#pragma unroll
      for (int ks = 0; ks < 4; ++ks)
#pragma unroll
        for (int n = 0; n < 4; ++n) {
          acc[n] = __builtin_amdgcn_mfma_f32_16x16x32_bf16(Ah[ks], Bh[n][ks], acc[n], 0, 0, 0);
          acc[n] = __builtin_amdgcn_mfma_f32_16x16x32_bf16(Al[ks], Bh[n][ks], acc[n], 0, 0, 0);
          acc[n] = __builtin_amdgcn_mfma_f32_16x16x32_bf16(Ah[ks], Bl[n][ks], acc[n], 0, 0, 0);
        }
#pragma unroll
      for (int n = 0; n < 4; ++n)
#pragma unroll
        for (int q = 0; q < 4; ++q) smax[n][q] = fmaxf(smax[n][q], acc[n][q]);
    }

    // ---- online softmax over this 64-col tile ----
    f32x4 pm;
#pragma unroll
    for (int q = 0; q < 4; ++q)
      pm[q] = fmaxf(fmaxf(smax[0][q], smax[1][q]), fmaxf(smax[2][q], smax[3][q]));
#pragma unroll
    for (int msk = 1; msk <= 8; msk <<= 1)
#pragma unroll
      for (int q = 0; q < 4; ++q) pm[q] = fmaxf(pm[q], __shfl_xor(pm[q], msk));

    f32x4 scale;
#pragma unroll
    for (int q = 0; q < 4; ++q) {
      const float mn = fmaxf(mrow[q], pm[q]);
      scale[q] = expf(mrow[q] - mn);
      mrow[q] = mn;
      lrow[q] *= scale[q];
    }
#pragma unroll
    for (int n = 0; n < 8; ++n)
#pragma unroll
      for (int q = 0; q < 4; ++q) acch[n][q] *= scale[q];

    f32x4 p[4], ps;
#pragma unroll
    for (int q = 0; q < 4; ++q) ps[q] = 0.f;
#pragma unroll
    for (int n = 0; n < 4; ++n)
#pragma unroll
      for (int q = 0; q < 4; ++q) {
        p[n][q] = expf(smax[n][q] - mrow[q]);
        ps[q] += p[n][q];
      }
#pragma unroll
    for (int msk = 1; msk <= 8; msk <<= 1)
#pragma unroll
      for (int q = 0; q < 4; ++q) ps[q] += __shfl_xor(ps[q], msk);
#pragma unroll
    for (int q = 0; q < 4; ++q) lrow[q] += ps[q];

    // ---- P (C/D layout) -> LDS -> A-frag layout (verified r11_C pattern) ----
#pragma unroll
    for (int n = 0; n < 4; ++n)
#pragma unroll
      for (int q = 0; q < 4; ++q)
        sP[w][lr * 4 + q][lc + 16 * n] = f2bf(p[n][q]);
    // wave-local write->read; compiler inserts lgkmcnt
    const short8v pa0 = *reinterpret_cast<const short8v*>(&sP[w][lc][lr * 8]);
    const short8v pa1 = *reinterpret_cast<const short8v*>(&sP[w][lc][32 + lr * 8]);

    // ---- PV: acch += P(16x64) . V(64x128), V split hi/lo ----
#pragma unroll
    for (int ksp = 0; ksp < 2; ++ksp) {
      const short8v pa = ksp ? pa1 : pa0;
      const int ksj = jt * 2 + ksp;  // global j/32
#pragma unroll
      for (int n = 0; n < 8; ++n) {
        const size_t off = (((size_t)b * 8 + n) * 24 + ksj) * 512 + (size_t)l * 8;
        const short8v vh = *reinterpret_cast<const short8v*>(VPh + off);
        const short8v vl = *reinterpret_cast<const short8v*>(VPl + off);
        acch[n] = __builtin_amdgcn_mfma_f32_16x16x32_bf16(pa, vh, acch[n], 0, 0, 0);
        acch[n] = __builtin_amdgcn_mfma_f32_16x16x32_bf16(pa, vl, acch[n], 0, 0, 0);
      }
    }
  }

  // ---- stash per-wave partials ----
#pragma unroll
  for (int n = 0; n < 8; ++n)
#pragma unroll
    for (int q = 0; q < 4; ++q)
      sOm[w][lr * 4 + q][n * 16 + lc] = acch[n][q];
  if (lc == 0) {
#pragma unroll
    for (int q = 0; q < 4; ++q) {
      sMw[w][lr * 4 + q] = mrow[q];
      sLw[w][lr * 4 + q] = lrow[q];
    }
  }
  __syncthreads();

  // ---- cross-wave merge + final write ----
  const int row = t >> 4;         // 0..15
  const int h0  = (t & 15) * 8;   // 0..120
  float mf = fmaxf(fmaxf(sMw[0][row], sMw[1][row]), fmaxf(sMw[2][row], sMw[3][row]));
  float lf = 0.f;
  float o[8] = {};
#pragma unroll
  for (int w2 = 0; w2 < 4; ++w2) {
    const float sc = expf(sMw[w2][row] - mf);
    lf += sLw[w2][row] * sc;
#pragma unroll
    for (int e = 0; e < 8; ++e) o[e] += sOm[w2][row][h0 + e] * sc;
  }
  const float inv = 1.0f / lf;
  float4 o0 = make_float4(o[0] * inv, o[1] * inv, o[2] * inv, o[3] * inv);
  float4 o1 = make_float4(o[4] * inv, o[5] * inv, o[6] * inv, o[7] * inv);
  float* Orow = O + ((size_t)(b * T_ + it16 * 16 + row)) * H_ + h0;
  *reinterpret_cast<float4*>(&Orow[0]) = o0;
  *reinterpret_cast<float4*>(&Orow[4]) = o1;
}

// ---------------------------------------------------------------------------
extern "C" void kernel_launch(void* const* d_in, const int* in_sizes, int n_in,
                              void* d_out, int out_size, void* d_ws, size_t ws_size,
                              hipStream_t stream) {
  const float* V = (const float*)d_in[0];  // f32 [B,T,H]
  const float* W = (const float*)d_in[1];  // f32 [F,H,H]
  if (n_in >= 2 && in_sizes[0] == F_ * H_ * H_) {
    V = (const float*)d_in[1];
    W = (const float*)d_in[0];
  }
  float* O = (float*)d_out;  // f32 [B,T,H]

  const size_t uf_bytes = (size_t)B_ * F_ * H_ * T_ * 2;  // 15,728,640
  const size_t vf_bytes = (size_t)B_ * H_ * T_ * 2;       //  1,572,864
  const size_t wf_bytes = (size_t)F_ * H_ * H_ * 2;       //    327,680
  const size_t need = 2 * uf_bytes + 4 * vf_bytes + 2 * wf_bytes;  // 38,404,096
  if (ws_size < need) return;

  char* base = (char*)d_ws;
  unsigned short* UFh = (unsigned short*)base;
  unsigned short* UFl = (unsigned short*)(base + uf_bytes);
  unsigned short* VFh = (unsigned short*)(base + 2 * uf_bytes);
  unsigned short* VFl = (unsigned short*)(base + 2 * uf_bytes + vf_bytes);
  unsigned short* VPh = (unsigned short*)(base + 2 * uf_bytes + 2 * vf_bytes);
  unsigned short* VPl = (unsigned short*)(base + 2 * uf_bytes + 3 * vf_bytes);
  unsigned short* WFh = (unsigned short*)(base + 2 * uf_bytes + 4 * vf_bytes);
  unsigned short* WFl = (unsigned short*)(base + 2 * uf_bytes + 4 * vf_bytes + wf_bytes);

  r10_PV<<<B_ * T_ * 16 / 256, 256, 0, stream>>>(V, VFh, VFl);
  r12_PW2<<<F_ * 8 * 4 * 64 / 256, 256, 0, stream>>>(W, WFh, WFl);
  r11_PW<<<B_ * 96 * 128 / 256, 256, 0, stream>>>(V, VPh, VPl);
  r12_A<<<B_ * F_ * (T_ / 64), 256, 0, stream>>>(VFh, VFl, WFh, WFl, UFh, UFl);
  r14_F<<<B_ * (T_ / 16), 256, 0, stream>>>(UFh, UFl, VFh, VFl, VPh, VPl, O);
}

// Round 15
// 79.849 us; speedup vs baseline: 2.3013x; 2.3013x over previous
//
#include <hip/hip_runtime.h>
#include <hip/hip_bf16.h>

#define B_ 8
#define T_ 768
#define H_ 128
#define F_ 10

using short8v = __attribute__((ext_vector_type(8))) short;
using f32x4   = __attribute__((ext_vector_type(4))) float;

__device__ __forceinline__ float bf2f(unsigned short s) {
  union { unsigned int u; float f; } w;
  w.u = ((unsigned int)s) << 16;
  return w.f;
}
__device__ __forceinline__ unsigned short f2bf(float x) {
  __hip_bfloat16 h = __float2bfloat16(x);  // RN
  return *reinterpret_cast<unsigned short*>(&h);
}
union Pk8 { uint4 u4; unsigned short s[8]; };

// ---------------------------------------------------------------------------
// r10_PV: V -> row-major fragments (rows = T index, K = H dim), hi/lo. (verified)
// ---------------------------------------------------------------------------
__global__ __launch_bounds__(256) void r10_PV(const float* __restrict__ V,
                                              unsigned short* __restrict__ VFh,
                                              unsigned short* __restrict__ VFl) {
  const int task = blockIdx.x * 256 + threadIdx.x;
  const int b  = task / (T_ * 16);
  const int r  = task % (T_ * 16);
  const int j  = r >> 4;
  const int ko = r & 15;
  const float* src = V + ((size_t)b * T_ + j) * H_ + ko * 8;
  const float4 v0 = *reinterpret_cast<const float4*>(src);
  const float4 v1 = *reinterpret_cast<const float4*>(src + 4);
  const float vv[8] = {v0.x, v0.y, v0.z, v0.w, v1.x, v1.y, v1.z, v1.w};
  Pk8 hi, lo;
#pragma unroll
  for (int e = 0; e < 8; ++e) {
    const unsigned short h = f2bf(vv[e]);
    hi.s[e] = h;
    lo.s[e] = f2bf(vv[e] - bf2f(h));
  }
  const size_t frag = ((size_t)b * 48 + (j >> 4)) * 4 + (ko >> 2);
  const size_t off = frag * 512 + ((size_t)((j & 15) + 16 * (ko & 3))) * 8;
  *reinterpret_cast<uint4*>(VFh + off) = hi.u4;
  *reinterpret_cast<uint4*>(VFl + off) = lo.u4;
}

// ---------------------------------------------------------------------------
// r12_PW2: W -> B-operand fragments (K = h, N = k), hi/lo.  (verified)
// ---------------------------------------------------------------------------
__global__ __launch_bounds__(256) void r12_PW2(const float* __restrict__ W,
                                               unsigned short* __restrict__ WFh,
                                               unsigned short* __restrict__ WFl) {
  const int tid = blockIdx.x * 256 + threadIdx.x;  // < 320*64
  const int frag = tid >> 6;
  const int l    = tid & 63;
  const int f    = frag >> 5;
  const int rest = frag & 31;
  const int n    = rest >> 2;
  const int ks   = rest & 3;
  const int k  = n * 16 + (l & 15);
  const int h0 = ks * 32 + ((l >> 4) * 8);
  Pk8 hi, lo;
#pragma unroll
  for (int e = 0; e < 8; ++e) {
    const float v = W[((size_t)f * H_ + h0 + e) * H_ + k];
    const unsigned short hh = f2bf(v);
    hi.s[e] = hh;
    lo.s[e] = f2bf(v - bf2f(hh));
  }
  const size_t off = (size_t)frag * 512 + (size_t)l * 8;
  *reinterpret_cast<uint4*>(WFh + off) = hi.u4;
  *reinterpret_cast<uint4*>(WFl + off) = lo.u4;
}

// ---------------------------------------------------------------------------
// r12_A: U = V @ W via split-bf16 MFMA -> UF fragments.  (verified, r13 swizzle)
// ---------------------------------------------------------------------------
__global__ __launch_bounds__(256) void r12_A(const unsigned short* __restrict__ VFh,
                                             const unsigned short* __restrict__ VFl,
                                             const unsigned short* __restrict__ WFh,
                                             const unsigned short* __restrict__ WFl,
                                             unsigned short* __restrict__ UFh,
                                             unsigned short* __restrict__ UFl) {
  __shared__ __align__(16) float fl[8192];
  const int blk = blockIdx.x;
  const int x     = blk & 7;        // XCD under round-robin dispatch
  const int local = blk >> 3;       // 0..119
  const int panel = x * 12 + local / 10;  // 0..95 (b,it)-panel
  const int f     = local % 10;
  const int b  = panel / 12;
  const int it = panel % 12;
  const int t  = threadIdx.x;
  const int w  = t >> 6;
  const int l  = t & 63;

  short8v Ah[4], Al[4];
#pragma unroll
  for (int ks = 0; ks < 4; ++ks) {
    const size_t off = (((size_t)b * 48 + it * 4 + w) * 4 + ks) * 512 + (size_t)l * 8;
    Ah[ks] = *reinterpret_cast<const short8v*>(VFh + off);
    Al[ks] = *reinterpret_cast<const short8v*>(VFl + off);
  }

  f32x4 acc[8];
#pragma unroll
  for (int n = 0; n < 8; ++n)
#pragma unroll
    for (int q = 0; q < 4; ++q) acc[n][q] = 0.f;

#pragma unroll
  for (int n = 0; n < 8; ++n)
#pragma unroll
    for (int ks = 0; ks < 4; ++ks) {
      const size_t off = ((size_t)(f * 8 + n) * 4 + ks) * 512 + (size_t)l * 8;
      const short8v bh = *reinterpret_cast<const short8v*>(WFh + off);
      const short8v bl = *reinterpret_cast<const short8v*>(WFl + off);
      acc[n] = __builtin_amdgcn_mfma_f32_16x16x32_bf16(Ah[ks], bh, acc[n], 0, 0, 0);
      acc[n] = __builtin_amdgcn_mfma_f32_16x16x32_bf16(Al[ks], bh, acc[n], 0, 0, 0);
      acc[n] = __builtin_amdgcn_mfma_f32_16x16x32_bf16(Ah[ks], bl, acc[n], 0, 0, 0);
    }

#pragma unroll
  for (int n = 0; n < 8; ++n)
#pragma unroll
    for (int q = 0; q < 4; ++q) {
      const int i_loc = w * 16 + (l >> 4) * 4 + q;
      const int k = n * 16 + (l & 15);
      const int ll = (i_loc & 15) + 16 * ((k >> 3) & 3);
      fl[((w * 4 + (k >> 5)) << 9) + ll * 8 + (k & 7)] = acc[n][q];
    }
  __syncthreads();
  const size_t ufbase = ((size_t)(b * F_ + f) * 192 + it * 16) * 512;
#pragma unroll
  for (int rr = 0; rr < 4; ++rr) {
    const int idx = rr * 2048 + t * 8;
    const float4 v0 = *reinterpret_cast<const float4*>(&fl[idx]);
    const float4 v1 = *reinterpret_cast<const float4*>(&fl[idx + 4]);
    const float vv[8] = {v0.x, v0.y, v0.z, v0.w, v1.x, v1.y, v1.z, v1.w};
    Pk8 hi, lo;
#pragma unroll
    for (int e = 0; e < 8; ++e) {
      const unsigned short h = f2bf(vv[e]);
      hi.s[e] = h;
      lo.s[e] = f2bf(vv[e] - bf2f(h));
    }
    *reinterpret_cast<uint4*>(UFh + ufbase + idx) = hi.u4;
    *reinterpret_cast<uint4*>(UFl + ufbase + idx) = lo.u4;
  }
}

// ---------------------------------------------------------------------------
// r10_B: S = max_f U_f V^T via split-bf16 MFMA.  (verified, r13 swizzle:
// the 12 jt-blocks of one (b,it) U-panel land consecutively on ONE XCD,
// and batch b's whole S output is produced on XCD b.)
// ---------------------------------------------------------------------------
__global__ __launch_bounds__(256) void r10_B(const unsigned short* __restrict__ UFh,
                                             const unsigned short* __restrict__ UFl,
                                             const unsigned short* __restrict__ VFh,
                                             const unsigned short* __restrict__ VFl,
                                             float* __restrict__ S) {
  const int blk = blockIdx.x;
  const int x     = blk & 7;
  const int local = blk >> 3;             // 0..143
  const int panel = x * 12 + local / 12;  // 0..95
  const int jt    = local % 12;
  const int b  = panel / 12;
  const int it = panel % 12;
  const int w  = threadIdx.x >> 6;
  const int l  = threadIdx.x & 63;

  short8v Bh[4][4], Bl[4][4];
#pragma unroll
  for (int n = 0; n < 4; ++n)
#pragma unroll
    for (int ks = 0; ks < 4; ++ks) {
      const size_t off =
          (((size_t)b * 48 + jt * 4 + n) * 4 + ks) * 512 + (size_t)l * 8;
      Bh[n][ks] = *reinterpret_cast<const short8v*>(VFh + off);
      Bl[n][ks] = *reinterpret_cast<const short8v*>(VFl + off);
    }

  f32x4 smax[4];
#pragma unroll
  for (int n = 0; n < 4; ++n)
#pragma unroll
    for (int q = 0; q < 4; ++q) smax[n][q] = -3.4e38f;

  for (int f = 0; f < F_; ++f) {
    const size_t abase = ((size_t)(b * F_ + f) * 48 + it * 4 + w) * 4;
    short8v Ah[4], Al[4];
#pragma unroll
    for (int ks = 0; ks < 4; ++ks) {
      const size_t off = (abase + ks) * 512 + (size_t)l * 8;
      Ah[ks] = *reinterpret_cast<const short8v*>(UFh + off);
      Al[ks] = *reinterpret_cast<const short8v*>(UFl + off);
    }
    f32x4 acc[4];
#pragma unroll
    for (int n = 0; n < 4; ++n)
#pragma unroll
      for (int q = 0; q < 4; ++q) acc[n][q] = 0.f;
#pragma unroll
    for (int ks = 0; ks < 4; ++ks)
#pragma unroll
      for (int n = 0; n < 4; ++n) {
        acc[n] = __builtin_amdgcn_mfma_f32_16x16x32_bf16(Ah[ks], Bh[n][ks], acc[n], 0, 0, 0);
        acc[n] = __builtin_amdgcn_mfma_f32_16x16x32_bf16(Al[ks], Bh[n][ks], acc[n], 0, 0, 0);
        acc[n] = __builtin_amdgcn_mfma_f32_16x16x32_bf16(Ah[ks], Bl[n][ks], acc[n], 0, 0, 0);
      }
#pragma unroll
    for (int n = 0; n < 4; ++n)
#pragma unroll
      for (int q = 0; q < 4; ++q) smax[n][q] = fmaxf(smax[n][q], acc[n][q]);
  }

  const int i0 = it * 64 + w * 16 + (l >> 4) * 4;
  const int j0 = jt * 64 + (l & 15);
#pragma unroll
  for (int n = 0; n < 4; ++n)
#pragma unroll
    for (int q = 0; q < 4; ++q)
      S[((size_t)b * T_ + i0 + q) * T_ + j0 + n * 16] = smax[n][q];
}

// ---------------------------------------------------------------------------
// r11_PW: V -> PV-B fragments (j as K dim, h as N dim), hi/lo.  (verified)
// ---------------------------------------------------------------------------
__global__ __launch_bounds__(256) void r11_PW(const float* __restrict__ V,
                                              unsigned short* __restrict__ VPh,
                                              unsigned short* __restrict__ VPl) {
  const int tid = blockIdx.x * 256 + threadIdx.x;  // < 98304
  const int h    = tid & 127;
  const int rest = tid >> 7;
  const int jo   = rest % 96;
  const int b    = rest / 96;
  const int j0   = jo * 8;

  Pk8 hi, lo;
#pragma unroll
  for (int e = 0; e < 8; ++e) {
    const float v = V[((size_t)b * T_ + j0 + e) * H_ + h];
    const unsigned short hh = f2bf(v);
    hi.s[e] = hh;
    lo.s[e] = f2bf(v - bf2f(hh));
  }
  const size_t frag = ((size_t)b * 8 + (h >> 4)) * 24 + (j0 >> 5);
  const size_t off = frag * 512 + ((size_t)((h & 15) + 16 * ((j0 >> 3) & 3))) * 8;
  *reinterpret_cast<uint4*>(VPh + off) = hi.u4;
  *reinterpret_cast<uint4*>(VPl + off) = lo.u4;
}

// ---------------------------------------------------------------------------
// r15_C: softmax -> P bf16 in LDS -> PV via MFMA.  512 threads (8 waves):
// softmax = 16 rows x 32 lanes; PV = 8 waves x 1 n-frag each (halved serial
// chain vs r11_C).  XCD-pinned: b = blk&7 -> reads batch-b S from XCD-b L2
// (r10_B's swizzle produced it there).  grid = 384.
// ---------------------------------------------------------------------------
__global__ __launch_bounds__(512) void r15_C(const unsigned short* __restrict__ VPh,
                                             const unsigned short* __restrict__ VPl,
                                             const float* __restrict__ S,
                                             float* __restrict__ O) {
  __shared__ __align__(16) unsigned short sP[16][776];
  __shared__ float sInv[16];
  const int blk = blockIdx.x;
  const int b    = blk & 7;
  const int it16 = blk >> 3;  // 0..47
  const int t  = threadIdx.x;
  const int r  = t >> 5;   // row 0..15
  const int c  = t & 31;   // lane-in-row (32 lanes)

  const float* Srow = S + (size_t)(b * T_ + it16 * 16) * T_;

  float4 buf[6];
  float m = -3.4e38f;
#pragma unroll
  for (int q = 0; q < 6; ++q) {
    const int j4 = c + q * 32;
    const float4 x = *reinterpret_cast<const float4*>(&Srow[r * T_ + j4 * 4]);
    buf[q] = x;
    m = fmaxf(m, fmaxf(fmaxf(x.x, x.y), fmaxf(x.z, x.w)));
  }
  m = fmaxf(m, __shfl_xor(m, 1));
  m = fmaxf(m, __shfl_xor(m, 2));
  m = fmaxf(m, __shfl_xor(m, 4));
  m = fmaxf(m, __shfl_xor(m, 8));
  m = fmaxf(m, __shfl_xor(m, 16));

  float l = 0.f;
#pragma unroll
  for (int q = 0; q < 6; ++q) {
    const int j4 = c + q * 32;
    float4 e;
    e.x = expf(buf[q].x - m);
    e.y = expf(buf[q].y - m);
    e.z = expf(buf[q].z - m);
    e.w = expf(buf[q].w - m);
    l += (e.x + e.y) + (e.z + e.w);
    ushort4 pb;
    pb.x = f2bf(e.x); pb.y = f2bf(e.y); pb.z = f2bf(e.z); pb.w = f2bf(e.w);
    *reinterpret_cast<ushort4*>(&sP[r][j4 * 4]) = pb;
  }
  l += __shfl_xor(l, 1);
  l += __shfl_xor(l, 2);
  l += __shfl_xor(l, 4);
  l += __shfl_xor(l, 8);
  l += __shfl_xor(l, 16);
  if (c == 0) sInv[r] = 1.0f / l;
  __syncthreads();

  // PV: wave w handles n-frag ht = w; rows 0-15 are the single m-frag.
  const int w  = t >> 6;   // 0..7
  const int lv = t & 63;
  f32x4 acc;
#pragma unroll
  for (int q = 0; q < 4; ++q) acc[q] = 0.f;

  const int arow = lv & 15;
  const int koct = lv >> 4;
#pragma unroll
  for (int ks = 0; ks < 24; ++ks) {
    const short8v pa =
        *reinterpret_cast<const short8v*>(&sP[arow][ks * 32 + koct * 8]);
    const size_t f0 = (((size_t)b * 8 + w) * 24 + ks) * 512 + (size_t)lv * 8;
    const short8v vh = *reinterpret_cast<const short8v*>(VPh + f0);
    const short8v vl = *reinterpret_cast<const short8v*>(VPl + f0);
    acc = __builtin_amdgcn_mfma_f32_16x16x32_bf16(pa, vh, acc, 0, 0, 0);
    acc = __builtin_amdgcn_mfma_f32_16x16x32_bf16(pa, vl, acc, 0, 0, 0);
  }

  // C/D: col = lv&15 (h within frag), row = (lv>>4)*4 + q (i within tile)
  const int hcol = lv & 15;
#pragma unroll
  for (int q = 0; q < 4; ++q) {
    const int irow = (lv >> 4) * 4 + q;
    const float inv = sInv[irow];
    const size_t obase = ((size_t)(b * T_ + it16 * 16 + irow)) * H_;
    O[obase + w * 16 + hcol] = acc[q] * inv;
  }
}

// ---------------------------------------------------------------------------
extern "C" void kernel_launch(void* const* d_in, const int* in_sizes, int n_in,
                              void* d_out, int out_size, void* d_ws, size_t ws_size,
                              hipStream_t stream) {
  const float* V = (const float*)d_in[0];  // f32 [B,T,H]
  const float* W = (const float*)d_in[1];  // f32 [F,H,H]
  if (n_in >= 2 && in_sizes[0] == F_ * H_ * H_) {
    V = (const float*)d_in[1];
    W = (const float*)d_in[0];
  }
  float* O = (float*)d_out;  // f32 [B,T,H]

  const size_t s_bytes  = (size_t)B_ * T_ * T_ * 4;       // 18,874,368
  const size_t uf_bytes = (size_t)B_ * F_ * H_ * T_ * 2;  // 15,728,640
  const size_t vf_bytes = (size_t)B_ * H_ * T_ * 2;       //  1,572,864
  const size_t wf_bytes = (size_t)F_ * H_ * H_ * 2;       //    327,680
  const size_t need = s_bytes + 2 * uf_bytes + 2 * vf_bytes;  // 53,477,376
  if (ws_size < need) return;

  char* base = (char*)d_ws;
  float* S  = (float*)base;  // [B,T,T]
  // WF overlays S: read only by r12_A, which completes before r10_B writes S.
  unsigned short* WFh = (unsigned short*)base;
  unsigned short* WFl = (unsigned short*)(base + wf_bytes);
  unsigned short* UFh = (unsigned short*)(base + s_bytes);
  unsigned short* UFl = (unsigned short*)(base + s_bytes + uf_bytes);
  unsigned short* VFh = (unsigned short*)(base + s_bytes + 2 * uf_bytes);
  unsigned short* VFl = (unsigned short*)(base + s_bytes + 2 * uf_bytes + vf_bytes);
  // VP overlays UF: written by r11_PW only after r10_B (UF's last reader).
  unsigned short* VPh = UFh;
  unsigned short* VPl = UFh + vf_bytes / 2;

  r10_PV<<<B_ * T_ * 16 / 256, 256, 0, stream>>>(V, VFh, VFl);
  r12_PW2<<<F_ * 8 * 4 * 64 / 256, 256, 0, stream>>>(W, WFh, WFl);
  r12_A<<<B_ * F_ * (T_ / 64), 256, 0, stream>>>(VFh, VFl, WFh, WFl, UFh, UFl);
  r10_B<<<B_ * (T_ / 64) * (T_ / 64), 256, 0, stream>>>(UFh, UFl, VFh, VFl, S);
  r11_PW<<<B_ * 96 * 128 / 256, 256, 0, stream>>>(V, VPh, VPl);
  r15_C<<<B_ * (T_ / 16), 512, 0, stream>>>(VPh, VPl, S, O);
}